// Round 15
// baseline (607.274 us; speedup 1.0000x reference)
//
#include <hip/hip_runtime.h>
#include <cstdint>
#include <cstddef>

#define NN    20000
#define EM    100000
#define EBN   20000
#define WID   32
#define KW    64
#define KIN   6
#define NDEPTH 4
#define GC    2080   // 64*32 kernel cols + 32 bias cols
#define NBL   9      // nodes per fuse-block (9 -> 75KB LDS -> 2 blocks/CU)
#define GR    2084   // padded LDS row
#define NQ    520    // GC/4 col-quads
#define TPB_F 576    // 9 waves
#define HSTR  12     // hg slots per k (9 used)

// ---------------- merged degree counts (src+dst, both graphs) ----------------

__global__ void k_count4(const int* __restrict__ ei, const int* __restrict__ eib,
                         int* __restrict__ cs1, int* __restrict__ cnt1,
                         int* __restrict__ csb, int* __restrict__ cntb) {
    int t = blockIdx.x * blockDim.x + threadIdx.x;
    if (t < EM) atomicAdd(&cs1[ei[t]], 1);
    else if (t < 2 * EM) atomicAdd(&cnt1[ei[t]], 1);           // ei[EM..2EM) = dst
    else if (t < 2 * EM + EBN) atomicAdd(&csb[eib[t - 2 * EM]], 1);
    else if (t < 2 * EM + 2 * EBN) atomicAdd(&cntb[eib[t - 2 * EM]], 1);
}

__global__ void k_inv2(const int* __restrict__ cnt1, float* __restrict__ inv1,
                       const int* __restrict__ cntb, float* __restrict__ invb) {
    int i = blockIdx.x * blockDim.x + threadIdx.x;
    if (i < NN) {
        int c = cnt1[i]; if (c < 1) c = 1;
        inv1[i] = 1.0f / (float)c;
    } else if (i < 2 * NN) {
        int c = cntb[i - NN]; if (c < 1) c = 1;
        invb[i - NN] = 1.0f / (float)c;
    }
}

// ---------------- dual scan (block 0: main, block 1: boundary) ----------------

__global__ __launch_bounds__(1024) void k_scan3(
        const int* __restrict__ csA, int* __restrict__ curA, int* __restrict__ arankA,
        int* __restrict__ anodesA, int* __restrict__ aoffA, int* __restrict__ dnaA, int EA,
        const int* __restrict__ csB, int* __restrict__ curB, int* __restrict__ arankB,
        int* __restrict__ anodesB, int* __restrict__ aoffB, int* __restrict__ dnaB, int EB) {
    __shared__ int part[1024];
    __shared__ int partf[1024];
    const int* cnt; int *cur, *arank, *anodes, *aoff, *dna; int E;
    if (blockIdx.x == 0) { cnt = csA; cur = curA; arank = arankA; anodes = anodesA; aoff = aoffA; dna = dnaA; E = EA; }
    else                 { cnt = csB; cur = curB; arank = arankB; anodes = anodesB; aoff = aoffB; dna = dnaB; E = EB; }
    int t = threadIdx.x;
    int per = (NN + 1023) / 1024;
    int base = t * per;
    int s = 0, f = 0;
    for (int i = 0; i < per; i++) {
        int idx = base + i;
        if (idx < NN) { int c = cnt[idx]; s += c; f += (c > 0) ? 1 : 0; }
    }
    part[t] = s; partf[t] = f;
    __syncthreads();
    for (int od = 1; od < 1024; od <<= 1) {
        int v  = (t >= od) ? part[t - od] : 0;
        int vf = (t >= od) ? partf[t - od] : 0;
        __syncthreads();
        part[t] += v; partf[t] += vf;
        __syncthreads();
    }
    int run  = (t > 0) ? part[t - 1] : 0;
    int runf = (t > 0) ? partf[t - 1] : 0;
    for (int i = 0; i < per; i++) {
        int idx = base + i;
        if (idx < NN) {
            int c = cnt[idx];
            cur[idx] = run;
            arank[idx] = runf;
            if (c > 0) { anodes[runf] = idx; aoff[runf] = run; runf++; }
            run += c;
        }
    }
    if (t == 1023) { dna[0] = partf[1023]; aoff[partf[1023]] = E; }
}

// ---------------- merged scatter + index build ----------------

__global__ void k_scatter3(const int* __restrict__ ei, int* __restrict__ cur1,
                           int* __restrict__ perm1, const int* __restrict__ eib,
                           int* __restrict__ curb, int* __restrict__ permb) {
    int t = blockIdx.x * blockDim.x + threadIdx.x;
    if (t < EM) { int p = atomicAdd(&cur1[ei[t]], 1); perm1[p] = t; }
    else if (t < EM + EBN) {
        int e = t - EM;
        int p = atomicAdd(&curb[eib[e]], 1); permb[p] = e;
    }
}

__global__ void k_permidx3(const int* __restrict__ ei, const int* __restrict__ perm1,
                           const int* __restrict__ arank1, int* __restrict__ rk1,
                           int* __restrict__ dst1,
                           const int* __restrict__ eib, const int* __restrict__ permb,
                           const int* __restrict__ arankb, int* __restrict__ rkb,
                           int* __restrict__ dstb) {
    int t = blockIdx.x * blockDim.x + threadIdx.x;
    if (t < EM) {
        int e = perm1[t];
        rk1[t] = arank1[ei[e]];
        dst1[t] = ei[EM + e];
    } else if (t < EM + EBN) {
        int i = t - EM;
        int e = permb[i];
        rkb[i] = arankb[eib[e]];
        dstb[i] = eib[EBN + e];
    }
}

// ---------------- M permute (+ root/bias prep folded in) ----------------

__global__ void k_permM3(const float* __restrict__ w3a, const float* __restrict__ b3a,
                         float* __restrict__ M1,
                         const float* __restrict__ w3b, const float* __restrict__ b3b,
                         float* __restrict__ M2,
                         const float* __restrict__ r1, const float* __restrict__ b1,
                         const float* __restrict__ r2, const float* __restrict__ b2,
                         float* __restrict__ rs, float* __restrict__ bs) {
    int t = blockIdx.x * blockDim.x + threadIdx.x;
    if (t < 32 * GC) {
        int i = t / GC, c = t % GC;
        M1[t] = (c < 2048) ? w3a[(c >> 5) * 1024 + i * 32 + (c & 31)]
                           : b3a[i * 32 + (c - 2048)];
    } else if (t < 64 * GC) {
        int u = t - 32 * GC;
        int i = u / GC, c = u % GC;
        M2[u] = (c < 2048) ? w3b[(c >> 5) * 1024 + i * 32 + (c & 31)]
                           : b3b[i * 32 + (c - 2048)];
    } else if (t < 64 * GC + 1024) {
        int i = t - 64 * GC;
        rs[i] = r1[i] + r2[i];
    } else if (t < 64 * GC + 1056) {
        int i = t - 64 * GC - 1024;
        bs[i] = b1[i] + b2[i];
    }
}

// ---------------- merged edge MLP (both graphs), permuted order ----------------

__global__ __launch_bounds__(256) void k_mlp3(
        const float* __restrict__ ea1, const int* __restrict__ perm1,
        const float* __restrict__ w1a, const float* __restrict__ b1a,
        const float* __restrict__ w2a, const float* __restrict__ b2a,
        float* __restrict__ K1,
        const float* __restrict__ ea2, const int* __restrict__ permb,
        const float* __restrict__ w1b, const float* __restrict__ b1b,
        const float* __restrict__ w2b, const float* __restrict__ b2b,
        float* __restrict__ K2, int nmb) {
    __shared__ float sw1[KIN * KW];
    __shared__ float sw2[KW * KW];
    __shared__ float sb1[KW];
    __shared__ float sb2[KW];
    const float *ea, *w1, *b1, *w2, *b2;
    const int* perm;
    float* K;
    int e, E;
    if ((int)blockIdx.x < nmb) {
        ea = ea1; perm = perm1; w1 = w1a; b1 = b1a; w2 = w2a; b2 = b2a; K = K1;
        e = blockIdx.x * 256 + threadIdx.x; E = EM;
    } else {
        ea = ea2; perm = permb; w1 = w1b; b1 = b1b; w2 = w2b; b2 = b2b; K = K2;
        e = (blockIdx.x - nmb) * 256 + threadIdx.x; E = EBN;
    }
    for (int i = threadIdx.x; i < KIN * KW; i += 256) sw1[i] = w1[i];
    for (int i = threadIdx.x; i < KW * KW; i += 256)  sw2[i] = w2[i];
    if (threadIdx.x < KW) { sb1[threadIdx.x] = b1[threadIdx.x]; sb2[threadIdx.x] = b2[threadIdx.x]; }
    __syncthreads();
    if (e >= E) return;
    int eo = perm[e];
    float a0 = ea[(size_t)eo * KIN + 0];
    float a1 = ea[(size_t)eo * KIN + 1];
    float a2 = ea[(size_t)eo * KIN + 2];
    float a3 = ea[(size_t)eo * KIN + 3];
    float a4 = ea[(size_t)eo * KIN + 4];
    float a5 = ea[(size_t)eo * KIN + 5];
    float t[KW];
#pragma unroll
    for (int j = 0; j < KW; j++) {
        float s = sb1[j];
        s += a0 * sw1[0 * KW + j];
        s += a1 * sw1[1 * KW + j];
        s += a2 * sw1[2 * KW + j];
        s += a3 * sw1[3 * KW + j];
        s += a4 * sw1[4 * KW + j];
        s += a5 * sw1[5 * KW + j];
        t[j] = fmaxf(s, 0.0f);
    }
#pragma unroll
    for (int h = 0; h < 2; h++) {
        int j0 = h * 32;
        float4 acc[8];
#pragma unroll
        for (int jj = 0; jj < 8; jj++)
            acc[jj] = *(const float4*)&sb2[j0 + jj * 4];
#pragma unroll
        for (int c = 0; c < KW; c++) {
            float tc = t[c];
#pragma unroll
            for (int jj = 0; jj < 8; jj++) {
                float4 w = *(const float4*)&sw2[c * KW + j0 + jj * 4];
                acc[jj].x += tc * w.x; acc[jj].y += tc * w.y;
                acc[jj].z += tc * w.z; acc[jj].w += tc * w.w;
            }
        }
#pragma unroll
        for (int jj = 0; jj < 8; jj++) {
            float4 r = acc[jj];
            r.x = fmaxf(r.x, 0.f); r.y = fmaxf(r.y, 0.f);
            r.z = fmaxf(r.z, 0.f); r.w = fmaxf(r.w, 0.f);
            *(float4*)&K[(size_t)e * KW + j0 + jj * 4] = r;
        }
    }
}

// ---------------- h init + per-group transposed gather (merged) ----------------
// hg layout: [group][k=32][slot=HSTR], NBL=9 slots used.

__global__ void k_h0g(const float* __restrict__ x, const float* __restrict__ fc1w,
        const float* __restrict__ fc1b, float* __restrict__ h,
        const int* __restrict__ arank1, const int* __restrict__ anodes1,
        const int* __restrict__ dna1, float* __restrict__ hg1,
        const int* __restrict__ arankb, const int* __restrict__ anodesb,
        const int* __restrict__ dnab, float* __restrict__ hgb) {
    int t = blockIdx.x * blockDim.x + threadIdx.x;
    if (t < NN * WID) {
        int n = t >> 5, j = t & 31;
        float v = x[n] * fc1w[j] + fc1b[j];
        h[t] = v;
        int r = arank1[n];
        if (r < dna1[0] && anodes1[r] == n)
            hg1[(r / NBL) * (32 * HSTR) + j * HSTR + (r % NBL)] = v;
    } else if (t < 2 * NN * WID) {
        int u = t - NN * WID;
        int n = u >> 5, j = u & 31;
        int r = arankb[n];
        if (r < dnab[0] && anodesb[r] == n)
            hgb[(r / NBL) * (32 * HSTR) + j * HSTR + (r % NBL)] = x[n] * fc1w[j] + fc1b[j];
    }
}

// ---------------- fused per-depth sweep, dual-graph, NBL=9, 576 threads ----------------
// 75KB LDS -> 2 blocks/CU = 18 waves/CU. Phase A: one thread per col-quad
// owns ALL 9 rows (M quad loaded exactly once per block -> 0.96GB L2/depth,
// 0.67x of NBL=6). Phase B: contiguous src-sorted edge range (unchanged).

__global__ __launch_bounds__(TPB_F, 2) void k_fuse3(
        const int* __restrict__ rkA, const int* __restrict__ dstA,
        const int* __restrict__ aoffA, const int* __restrict__ dnaA,
        const float* __restrict__ KA, const float* __restrict__ MA,
        const float* __restrict__ hgA, float* __restrict__ aggA,
        const int* __restrict__ rkB, const int* __restrict__ dstB,
        const int* __restrict__ aoffB, const int* __restrict__ dnaB,
        const float* __restrict__ KB, const float* __restrict__ MB,
        const float* __restrict__ hgB, float* __restrict__ aggB,
        int nblkA) {
    __shared__ float sG[NBL * GR];   // 75.0 KB
    const int *rk_s, *dst_s, *aoff;
    const float *Ks, *M, *hg;
    float* agg;
    int bid, na;
    if ((int)blockIdx.x < nblkA) {
        bid = blockIdx.x; na = dnaA[0];
        rk_s = rkA; dst_s = dstA; aoff = aoffA; Ks = KA; M = MA; hg = hgA; agg = aggA;
    } else {
        bid = blockIdx.x - nblkA; na = dnaB[0];
        rk_s = rkB; dst_s = dstB; aoff = aoffB; Ks = KB; M = MB; hg = hgB; agg = aggB;
    }
    int a0 = bid * NBL;
    if (a0 >= na) return;
    int t = threadIdx.x;
    // phase A: one col-quad per thread, all 9 rows
    if (t < NQ) {
        int col = t * 4;
        const float* hb = hg + (size_t)bid * (32 * HSTR);   // wave-uniform loads
        float4 acc[NBL];
#pragma unroll
        for (int r = 0; r < NBL; r++) acc[r] = make_float4(0.f, 0.f, 0.f, 0.f);
#pragma unroll 8
        for (int k = 0; k < 32; k++) {
            float4 mv = *(const float4*)&M[(size_t)k * GC + col];
            float4 ha = *(const float4*)&hb[k * HSTR];
            float4 h2 = *(const float4*)&hb[k * HSTR + 4];
            float  hc = hb[k * HSTR + 8];
            float hv[NBL] = {ha.x, ha.y, ha.z, ha.w, h2.x, h2.y, h2.z, h2.w, hc};
#pragma unroll
            for (int r = 0; r < NBL; r++) {
                acc[r].x += hv[r] * mv.x; acc[r].y += hv[r] * mv.y;
                acc[r].z += hv[r] * mv.z; acc[r].w += hv[r] * mv.w;
            }
        }
#pragma unroll
        for (int r = 0; r < NBL; r++)
            *(float4*)&sG[r * GR + col] = acc[r];
    }
    __syncthreads();
    // phase B: 72 groups of 8 lanes, 1 edge per group per pass
    int a1 = a0 + NBL; if (a1 > na) a1 = na;
    int e_lo = aoff[a0];
    int e_hi = aoff[a1];
    int g = t >> 3;
    int q4 = (t & 7) * 4;
    for (int e = e_lo + g; e < e_hi; e += TPB_F / 8) {
        int row = rk_s[e] - a0;
        int dst = dst_s[e];
        const float* Kr = Ks + (size_t)e * KW;
        int gb = row * GR;
        float4 v0 = *(const float4*)&sG[gb + 2048 + q4];   // bias-fold column
        float4 v1 = make_float4(0.f, 0.f, 0.f, 0.f);
        float4 v2 = v1, v3 = v1;
#pragma unroll
        for (int c4 = 0; c4 < 16; c4++) {
            float4 kv = *(const float4*)&Kr[c4 * 4];
            float4 g0 = *(const float4*)&sG[gb + (c4 * 4 + 0) * 32 + q4];
            float4 g1 = *(const float4*)&sG[gb + (c4 * 4 + 1) * 32 + q4];
            float4 g2 = *(const float4*)&sG[gb + (c4 * 4 + 2) * 32 + q4];
            float4 g3 = *(const float4*)&sG[gb + (c4 * 4 + 3) * 32 + q4];
            v0.x += kv.x * g0.x; v0.y += kv.x * g0.y; v0.z += kv.x * g0.z; v0.w += kv.x * g0.w;
            v1.x += kv.y * g1.x; v1.y += kv.y * g1.y; v1.z += kv.y * g1.z; v1.w += kv.y * g1.w;
            v2.x += kv.z * g2.x; v2.y += kv.z * g2.y; v2.z += kv.z * g2.z; v2.w += kv.z * g2.w;
            v3.x += kv.w * g3.x; v3.y += kv.w * g3.y; v3.z += kv.w * g3.z; v3.w += kv.w * g3.w;
        }
        float4 m;
        m.x = v0.x + v1.x + v2.x + v3.x;
        m.y = v0.y + v1.y + v2.y + v3.y;
        m.z = v0.z + v1.z + v2.z + v3.z;
        m.w = v0.w + v1.w + v2.w + v3.w;
        float* ap = agg + (size_t)dst * WID + q4;
        unsafeAtomicAdd(ap + 0, m.x);
        unsafeAtomicAdd(ap + 1, m.y);
        unsafeAtomicAdd(ap + 2, m.z);
        unsafeAtomicAdd(ap + 3, m.w);
    }
}

// ---------------- node update (in place) + hg regather for next depth ----------------

__global__ __launch_bounds__(256) void k_node2(float* __restrict__ h,
        const float* __restrict__ agg1, const float* __restrict__ aggb,
        const float* __restrict__ inv1, const float* __restrict__ invb,
        const float* __restrict__ x, const float* __restrict__ fc1w,
        const float* __restrict__ fc1b,
        const float* __restrict__ rs, const float* __restrict__ bs,
        const int* __restrict__ arank1, const int* __restrict__ anodes1,
        const int* __restrict__ dna1, float* __restrict__ hg1,
        const int* __restrict__ arankb, const int* __restrict__ anodesb,
        const int* __restrict__ dnab, float* __restrict__ hgb) {
    __shared__ float sR[1024];
    __shared__ float sB[32];
    for (int i = threadIdx.x; i < 1024; i += 256) sR[i] = rs[i];
    if (threadIdx.x < 32) sB[threadIdx.x] = bs[threadIdx.x];
    __syncthreads();
    int t = blockIdx.x * 256 + threadIdx.x;
    if (t >= NN * WID) return;
    int n = t >> 5, j = t & 31;
    float s = agg1[t] * inv1[n] + aggb[t] * invb[n] + sB[j];
    const float* hr = h + (size_t)n * WID;
#pragma unroll
    for (int i = 0; i < 32; i++) s += hr[i] * sR[i * 32 + j];
    float h0v = x[n] * fc1w[j] + fc1b[j];
    float val = fmaxf(s, 0.0f) + h0v;
    h[t] = val;   // wave-lockstep: all row reads precede any store in program order
    int r1 = arank1[n];
    if (r1 < dna1[0] && anodes1[r1] == n)
        hg1[(r1 / NBL) * (32 * HSTR) + j * HSTR + (r1 % NBL)] = val;
    int rb = arankb[n];
    if (rb < dnab[0] && anodesb[rb] == n)
        hgb[(rb / NBL) * (32 * HSTR) + j * HSTR + (rb % NBL)] = val;
}

__global__ void k_fc2(const float* __restrict__ h, const float* __restrict__ w,
                      const float* __restrict__ b, float* __restrict__ out) {
    int n = blockIdx.x * blockDim.x + threadIdx.x;
    if (n >= NN) return;
    const float4* hv = (const float4*)(h + (size_t)n * WID);
    const float4* wv = (const float4*)w;
    float s = b[0];
#pragma unroll
    for (int q = 0; q < 8; q++) {
        float4 a = hv[q], c = wv[q];
        s += a.x * c.x + a.y * c.y + a.z * c.z + a.w * c.w;
    }
    out[n] = s;
}

// ---------------- launch ----------------

extern "C" void kernel_launch(void* const* d_in, const int* in_sizes, int n_in,
                              void* d_out, int out_size, void* d_ws, size_t ws_size,
                              hipStream_t stream) {
    const float* x    = (const float*)d_in[0];
    const int*   ei   = (const int*)d_in[1];
    const float* ea   = (const float*)d_in[2];
    const int*   eib  = (const int*)d_in[3];
    const float* eab  = (const float*)d_in[4];
    const float* fc1w = (const float*)d_in[5];
    const float* fc1b = (const float*)d_in[6];
    const float* fc2w = (const float*)d_in[7];
    const float* fc2b = (const float*)d_in[8];
    const float* k1w1 = (const float*)d_in[9];
    const float* k1b1 = (const float*)d_in[10];
    const float* k1w2 = (const float*)d_in[11];
    const float* k1b2 = (const float*)d_in[12];
    const float* k1w3 = (const float*)d_in[13];
    const float* k1b3 = (const float*)d_in[14];
    const float* root1= (const float*)d_in[15];
    const float* bias1= (const float*)d_in[16];
    const float* k2w1 = (const float*)d_in[17];
    const float* k2b1 = (const float*)d_in[18];
    const float* k2w2 = (const float*)d_in[19];
    const float* k2b2 = (const float*)d_in[20];
    const float* k2w3 = (const float*)d_in[21];
    const float* k2b3 = (const float*)d_in[22];
    const float* root2= (const float*)d_in[23];
    const float* bias2= (const float*)d_in[24];

    float* p = (float*)d_ws;
    auto alloc = [&](size_t nflt) { float* r = p; p += nflt; return r; };
    int nblkA = (NN + NBL - 1) / NBL;           // 2223
    float* K1   = alloc((size_t)EM * KW);     // sorted (by src) order
    float* Kb   = alloc((size_t)EBN * KW);
    float* hA   = alloc((size_t)NN * WID);
    float* agg1 = alloc((size_t)NN * WID);    // agg1+aggb contiguous: single memset
    float* aggb = alloc((size_t)NN * WID);
    float* hg1  = alloc((size_t)(nblkA + 2) * 32 * HSTR);
    float* hgb  = alloc((size_t)(nblkA + 2) * 32 * HSTR);
    float* inv1 = alloc(NN);
    float* invb = alloc(NN);
    float* rs   = alloc(1024);
    float* bs   = alloc(32);
    int*   cnt1 = (int*)alloc(NN);   // cnt1,cntb,cs1,csb contiguous: single memset
    int*   cntb = (int*)alloc(NN);
    int*   cs1  = (int*)alloc(NN);
    int*   csb  = (int*)alloc(NN);
    int*   cur1 = (int*)alloc(NN);
    int*   curb = (int*)alloc(NN);
    int*   arank1 = (int*)alloc(NN);
    int*   arankb = (int*)alloc(NN);
    int*   anodes1= (int*)alloc(NN);
    int*   anodesb= (int*)alloc(NN);
    int*   aoff1  = (int*)alloc(NN + 1);
    int*   aoffb  = (int*)alloc(NN + 1);
    int*   dna1   = (int*)alloc(1);
    int*   dnab   = (int*)alloc(1);
    int*   perm1= (int*)alloc(EM);
    int*   permb= (int*)alloc(EBN);
    int*   rk1  = (int*)alloc(EM);
    int*   dst1 = (int*)alloc(EM);
    int*   rkb  = (int*)alloc(EBN);
    int*   dstb = (int*)alloc(EBN);
    float* M1   = alloc(32 * GC);
    float* M2   = alloc(32 * GC);

    hipMemsetAsync(cnt1, 0, 4 * NN * sizeof(int), stream);
    k_count4<<<(2 * EM + 2 * EBN + 255) / 256, 256, 0, stream>>>(ei, eib, cs1, cnt1, csb, cntb);
    k_scan3<<<2, 1024, 0, stream>>>(cs1, cur1, arank1, anodes1, aoff1, dna1, EM,
                                    csb, curb, arankb, anodesb, aoffb, dnab, EBN);
    k_inv2<<<(2 * NN + 255) / 256, 256, 0, stream>>>(cnt1, inv1, cntb, invb);
    k_scatter3<<<(EM + EBN + 255) / 256, 256, 0, stream>>>(ei, cur1, perm1, eib, curb, permb);
    k_permidx3<<<(EM + EBN + 255) / 256, 256, 0, stream>>>(ei, perm1, arank1, rk1, dst1,
                                                           eib, permb, arankb, rkb, dstb);
    int nmb = (EM + 255) / 256;
    k_mlp3<<<nmb + (EBN + 255) / 256, 256, 0, stream>>>(
        ea, perm1, k1w1, k1b1, k1w2, k1b2, K1,
        eab, permb, k2w1, k2b1, k2w2, k2b2, Kb, nmb);
    k_permM3<<<(64 * GC + 1056 + 255) / 256, 256, 0, stream>>>(
        k1w3, k1b3, M1, k2w3, k2b3, M2, root1, bias1, root2, bias2, rs, bs);
    k_h0g<<<(2 * NN * WID + 255) / 256, 256, 0, stream>>>(x, fc1w, fc1b, hA,
                                                          arank1, anodes1, dna1, hg1,
                                                          arankb, anodesb, dnab, hgb);

    int fgrid = nblkA * 2;                      // main + boundary halves
    for (int d = 0; d < NDEPTH; d++) {
        hipMemsetAsync(agg1, 0, (size_t)2 * NN * WID * sizeof(float), stream);
        k_fuse3<<<fgrid, TPB_F, 0, stream>>>(rk1, dst1, aoff1, dna1, K1, M1, hg1, agg1,
                                             rkb, dstb, aoffb, dnab, Kb, M2, hgb, aggb,
                                             nblkA);
        k_node2<<<(NN * WID + 255) / 256, 256, 0, stream>>>(hA, agg1, aggb, inv1, invb,
                                                            x, fc1w, fc1b, rs, bs,
                                                            arank1, anodes1, dna1, hg1,
                                                            arankb, anodesb, dnab, hgb);
    }
    k_fc2<<<(NN + 255) / 256, 256, 0, stream>>>(hA, fc2w, fc2b, (float*)d_out);
}

// Round 16
// 590.276 us; speedup vs baseline: 1.0288x; 1.0288x over previous
//
#include <hip/hip_runtime.h>
#include <cstdint>
#include <cstddef>

#define NN    20000
#define EM    100000
#define EBN   20000
#define WID   32
#define KW    64
#define KIN   6
#define NDEPTH 4
#define GC    2080   // 64*32 kernel cols + 32 bias cols
#define NBL   9      // nodes per fuse-block (9 -> 75KB LDS -> 2 blocks/CU)
#define GR    2084   // padded LDS row
#define NQ    520    // GC/4 col-quads
#define TPB_F 576    // 9 waves
#define HSTR  12     // hg slots per k (9 used)

// ---------------- merged degree counts (src+dst, both graphs) ----------------

__global__ void k_count4(const int* __restrict__ ei, const int* __restrict__ eib,
                         int* __restrict__ cs1, int* __restrict__ cnt1,
                         int* __restrict__ csb, int* __restrict__ cntb) {
    int t = blockIdx.x * blockDim.x + threadIdx.x;
    if (t < EM) atomicAdd(&cs1[ei[t]], 1);
    else if (t < 2 * EM) atomicAdd(&cnt1[ei[t]], 1);           // ei[EM..2EM) = dst
    else if (t < 2 * EM + EBN) atomicAdd(&csb[eib[t - 2 * EM]], 1);
    else if (t < 2 * EM + 2 * EBN) atomicAdd(&cntb[eib[t - 2 * EM]], 1);
}

// ---------------- dual scan (block 0: main, block 1: boundary) ----------------

__global__ __launch_bounds__(1024) void k_scan3(
        const int* __restrict__ csA, int* __restrict__ curA, int* __restrict__ arankA,
        int* __restrict__ anodesA, int* __restrict__ aoffA, int* __restrict__ dnaA, int EA,
        const int* __restrict__ csB, int* __restrict__ curB, int* __restrict__ arankB,
        int* __restrict__ anodesB, int* __restrict__ aoffB, int* __restrict__ dnaB, int EB) {
    __shared__ int part[1024];
    __shared__ int partf[1024];
    const int* cnt; int *cur, *arank, *anodes, *aoff, *dna; int E;
    if (blockIdx.x == 0) { cnt = csA; cur = curA; arank = arankA; anodes = anodesA; aoff = aoffA; dna = dnaA; E = EA; }
    else                 { cnt = csB; cur = curB; arank = arankB; anodes = anodesB; aoff = aoffB; dna = dnaB; E = EB; }
    int t = threadIdx.x;
    int per = (NN + 1023) / 1024;
    int base = t * per;
    int s = 0, f = 0;
    for (int i = 0; i < per; i++) {
        int idx = base + i;
        if (idx < NN) { int c = cnt[idx]; s += c; f += (c > 0) ? 1 : 0; }
    }
    part[t] = s; partf[t] = f;
    __syncthreads();
    for (int od = 1; od < 1024; od <<= 1) {
        int v  = (t >= od) ? part[t - od] : 0;
        int vf = (t >= od) ? partf[t - od] : 0;
        __syncthreads();
        part[t] += v; partf[t] += vf;
        __syncthreads();
    }
    int run  = (t > 0) ? part[t - 1] : 0;
    int runf = (t > 0) ? partf[t - 1] : 0;
    for (int i = 0; i < per; i++) {
        int idx = base + i;
        if (idx < NN) {
            int c = cnt[idx];
            cur[idx] = run;
            arank[idx] = runf;
            if (c > 0) { anodes[runf] = idx; aoff[runf] = run; runf++; }
            run += c;
        }
    }
    if (t == 1023) { dna[0] = partf[1023]; aoff[partf[1023]] = E; }
}

// ---------------- merged scatter + index build ----------------

__global__ void k_scatter3(const int* __restrict__ ei, int* __restrict__ cur1,
                           int* __restrict__ perm1, const int* __restrict__ eib,
                           int* __restrict__ curb, int* __restrict__ permb) {
    int t = blockIdx.x * blockDim.x + threadIdx.x;
    if (t < EM) { int p = atomicAdd(&cur1[ei[t]], 1); perm1[p] = t; }
    else if (t < EM + EBN) {
        int e = t - EM;
        int p = atomicAdd(&curb[eib[e]], 1); permb[p] = e;
    }
}

// rk/dst index build + inv (mean denominators) folded in

__global__ void k_permidx3(const int* __restrict__ ei, const int* __restrict__ perm1,
                           const int* __restrict__ arank1, int* __restrict__ rk1,
                           int* __restrict__ dst1,
                           const int* __restrict__ eib, const int* __restrict__ permb,
                           const int* __restrict__ arankb, int* __restrict__ rkb,
                           int* __restrict__ dstb,
                           const int* __restrict__ cnt1, float* __restrict__ inv1,
                           const int* __restrict__ cntb, float* __restrict__ invb) {
    int t = blockIdx.x * blockDim.x + threadIdx.x;
    if (t < EM) {
        int e = perm1[t];
        rk1[t] = arank1[ei[e]];
        dst1[t] = ei[EM + e];
    } else if (t < EM + EBN) {
        int i = t - EM;
        int e = permb[i];
        rkb[i] = arankb[eib[e]];
        dstb[i] = eib[EBN + e];
    } else if (t < EM + EBN + NN) {
        int i = t - EM - EBN;
        int c = cnt1[i]; if (c < 1) c = 1;
        inv1[i] = 1.0f / (float)c;
    } else if (t < EM + EBN + 2 * NN) {
        int i = t - EM - EBN - NN;
        int c = cntb[i]; if (c < 1) c = 1;
        invb[i] = 1.0f / (float)c;
    }
}

// ---------------- M permute (+ root/bias prep folded in) ----------------

__global__ void k_permM3(const float* __restrict__ w3a, const float* __restrict__ b3a,
                         float* __restrict__ M1,
                         const float* __restrict__ w3b, const float* __restrict__ b3b,
                         float* __restrict__ M2,
                         const float* __restrict__ r1, const float* __restrict__ b1,
                         const float* __restrict__ r2, const float* __restrict__ b2,
                         float* __restrict__ rs, float* __restrict__ bs) {
    int t = blockIdx.x * blockDim.x + threadIdx.x;
    if (t < 32 * GC) {
        int i = t / GC, c = t % GC;
        M1[t] = (c < 2048) ? w3a[(c >> 5) * 1024 + i * 32 + (c & 31)]
                           : b3a[i * 32 + (c - 2048)];
    } else if (t < 64 * GC) {
        int u = t - 32 * GC;
        int i = u / GC, c = u % GC;
        M2[u] = (c < 2048) ? w3b[(c >> 5) * 1024 + i * 32 + (c & 31)]
                           : b3b[i * 32 + (c - 2048)];
    } else if (t < 64 * GC + 1024) {
        int i = t - 64 * GC;
        rs[i] = r1[i] + r2[i];
    } else if (t < 64 * GC + 1056) {
        int i = t - 64 * GC - 1024;
        bs[i] = b1[i] + b2[i];
    }
}

// ---------------- merged edge MLP (both graphs), permuted order ----------------

__global__ __launch_bounds__(256) void k_mlp3(
        const float* __restrict__ ea1, const int* __restrict__ perm1,
        const float* __restrict__ w1a, const float* __restrict__ b1a,
        const float* __restrict__ w2a, const float* __restrict__ b2a,
        float* __restrict__ K1,
        const float* __restrict__ ea2, const int* __restrict__ permb,
        const float* __restrict__ w1b, const float* __restrict__ b1b,
        const float* __restrict__ w2b, const float* __restrict__ b2b,
        float* __restrict__ K2, int nmb) {
    __shared__ float sw1[KIN * KW];
    __shared__ float sw2[KW * KW];
    __shared__ float sb1[KW];
    __shared__ float sb2[KW];
    const float *ea, *w1, *b1, *w2, *b2;
    const int* perm;
    float* K;
    int e, E;
    if ((int)blockIdx.x < nmb) {
        ea = ea1; perm = perm1; w1 = w1a; b1 = b1a; w2 = w2a; b2 = b2a; K = K1;
        e = blockIdx.x * 256 + threadIdx.x; E = EM;
    } else {
        ea = ea2; perm = permb; w1 = w1b; b1 = b1b; w2 = w2b; b2 = b2b; K = K2;
        e = (blockIdx.x - nmb) * 256 + threadIdx.x; E = EBN;
    }
    for (int i = threadIdx.x; i < KIN * KW; i += 256) sw1[i] = w1[i];
    for (int i = threadIdx.x; i < KW * KW; i += 256)  sw2[i] = w2[i];
    if (threadIdx.x < KW) { sb1[threadIdx.x] = b1[threadIdx.x]; sb2[threadIdx.x] = b2[threadIdx.x]; }
    __syncthreads();
    if (e >= E) return;
    int eo = perm[e];
    float a0 = ea[(size_t)eo * KIN + 0];
    float a1 = ea[(size_t)eo * KIN + 1];
    float a2 = ea[(size_t)eo * KIN + 2];
    float a3 = ea[(size_t)eo * KIN + 3];
    float a4 = ea[(size_t)eo * KIN + 4];
    float a5 = ea[(size_t)eo * KIN + 5];
    float t[KW];
#pragma unroll
    for (int j = 0; j < KW; j++) {
        float s = sb1[j];
        s += a0 * sw1[0 * KW + j];
        s += a1 * sw1[1 * KW + j];
        s += a2 * sw1[2 * KW + j];
        s += a3 * sw1[3 * KW + j];
        s += a4 * sw1[4 * KW + j];
        s += a5 * sw1[5 * KW + j];
        t[j] = fmaxf(s, 0.0f);
    }
#pragma unroll
    for (int h = 0; h < 2; h++) {
        int j0 = h * 32;
        float4 acc[8];
#pragma unroll
        for (int jj = 0; jj < 8; jj++)
            acc[jj] = *(const float4*)&sb2[j0 + jj * 4];
#pragma unroll
        for (int c = 0; c < KW; c++) {
            float tc = t[c];
#pragma unroll
            for (int jj = 0; jj < 8; jj++) {
                float4 w = *(const float4*)&sw2[c * KW + j0 + jj * 4];
                acc[jj].x += tc * w.x; acc[jj].y += tc * w.y;
                acc[jj].z += tc * w.z; acc[jj].w += tc * w.w;
            }
        }
#pragma unroll
        for (int jj = 0; jj < 8; jj++) {
            float4 r = acc[jj];
            r.x = fmaxf(r.x, 0.f); r.y = fmaxf(r.y, 0.f);
            r.z = fmaxf(r.z, 0.f); r.w = fmaxf(r.w, 0.f);
            *(float4*)&K[(size_t)e * KW + j0 + jj * 4] = r;
        }
    }
}

// ---------------- h init + per-group transposed gather + agg zero (merged) ----------------
// hg layout: [group][k=32][slot=HSTR], NBL=9 slots used. aggz = agg1 base
// (agg1+aggb contiguous, exactly 2*NN*WID floats = this grid).

__global__ void k_h0g(const float* __restrict__ x, const float* __restrict__ fc1w,
        const float* __restrict__ fc1b, float* __restrict__ h,
        const int* __restrict__ arank1, const int* __restrict__ anodes1,
        const int* __restrict__ dna1, float* __restrict__ hg1,
        const int* __restrict__ arankb, const int* __restrict__ anodesb,
        const int* __restrict__ dnab, float* __restrict__ hgb,
        float* __restrict__ aggz) {
    int t = blockIdx.x * blockDim.x + threadIdx.x;
    if (t < 2 * NN * WID) aggz[t] = 0.0f;
    if (t < NN * WID) {
        int n = t >> 5, j = t & 31;
        float v = x[n] * fc1w[j] + fc1b[j];
        h[t] = v;
        int r = arank1[n];
        if (r < dna1[0] && anodes1[r] == n)
            hg1[(r / NBL) * (32 * HSTR) + j * HSTR + (r % NBL)] = v;
    } else if (t < 2 * NN * WID) {
        int u = t - NN * WID;
        int n = u >> 5, j = u & 31;
        int r = arankb[n];
        if (r < dnab[0] && anodesb[r] == n)
            hgb[(r / NBL) * (32 * HSTR) + j * HSTR + (r % NBL)] = x[n] * fc1w[j] + fc1b[j];
    }
}

// ---------------- fused per-depth sweep, dual-graph, NBL=9, 576 threads ----------------
// (unchanged from round 15: 75KB LDS -> 2 blocks/CU; locally converged ~108us)

__global__ __launch_bounds__(TPB_F, 2) void k_fuse3(
        const int* __restrict__ rkA, const int* __restrict__ dstA,
        const int* __restrict__ aoffA, const int* __restrict__ dnaA,
        const float* __restrict__ KA, const float* __restrict__ MA,
        const float* __restrict__ hgA, float* __restrict__ aggA,
        const int* __restrict__ rkB, const int* __restrict__ dstB,
        const int* __restrict__ aoffB, const int* __restrict__ dnaB,
        const float* __restrict__ KB, const float* __restrict__ MB,
        const float* __restrict__ hgB, float* __restrict__ aggB,
        int nblkA) {
    __shared__ float sG[NBL * GR];   // 75.0 KB
    const int *rk_s, *dst_s, *aoff;
    const float *Ks, *M, *hg;
    float* agg;
    int bid, na;
    if ((int)blockIdx.x < nblkA) {
        bid = blockIdx.x; na = dnaA[0];
        rk_s = rkA; dst_s = dstA; aoff = aoffA; Ks = KA; M = MA; hg = hgA; agg = aggA;
    } else {
        bid = blockIdx.x - nblkA; na = dnaB[0];
        rk_s = rkB; dst_s = dstB; aoff = aoffB; Ks = KB; M = MB; hg = hgB; agg = aggB;
    }
    int a0 = bid * NBL;
    if (a0 >= na) return;
    int t = threadIdx.x;
    // phase A: one col-quad per thread, all 9 rows
    if (t < NQ) {
        int col = t * 4;
        const float* hb = hg + (size_t)bid * (32 * HSTR);   // wave-uniform loads
        float4 acc[NBL];
#pragma unroll
        for (int r = 0; r < NBL; r++) acc[r] = make_float4(0.f, 0.f, 0.f, 0.f);
#pragma unroll 8
        for (int k = 0; k < 32; k++) {
            float4 mv = *(const float4*)&M[(size_t)k * GC + col];
            float4 ha = *(const float4*)&hb[k * HSTR];
            float4 h2 = *(const float4*)&hb[k * HSTR + 4];
            float  hc = hb[k * HSTR + 8];
            float hv[NBL] = {ha.x, ha.y, ha.z, ha.w, h2.x, h2.y, h2.z, h2.w, hc};
#pragma unroll
            for (int r = 0; r < NBL; r++) {
                acc[r].x += hv[r] * mv.x; acc[r].y += hv[r] * mv.y;
                acc[r].z += hv[r] * mv.z; acc[r].w += hv[r] * mv.w;
            }
        }
#pragma unroll
        for (int r = 0; r < NBL; r++)
            *(float4*)&sG[r * GR + col] = acc[r];
    }
    __syncthreads();
    // phase B: 72 groups of 8 lanes, 1 edge per group per pass
    int a1 = a0 + NBL; if (a1 > na) a1 = na;
    int e_lo = aoff[a0];
    int e_hi = aoff[a1];
    int g = t >> 3;
    int q4 = (t & 7) * 4;
    for (int e = e_lo + g; e < e_hi; e += TPB_F / 8) {
        int row = rk_s[e] - a0;
        int dst = dst_s[e];
        const float* Kr = Ks + (size_t)e * KW;
        int gb = row * GR;
        float4 v0 = *(const float4*)&sG[gb + 2048 + q4];   // bias-fold column
        float4 v1 = make_float4(0.f, 0.f, 0.f, 0.f);
        float4 v2 = v1, v3 = v1;
#pragma unroll
        for (int c4 = 0; c4 < 16; c4++) {
            float4 kv = *(const float4*)&Kr[c4 * 4];
            float4 g0 = *(const float4*)&sG[gb + (c4 * 4 + 0) * 32 + q4];
            float4 g1 = *(const float4*)&sG[gb + (c4 * 4 + 1) * 32 + q4];
            float4 g2 = *(const float4*)&sG[gb + (c4 * 4 + 2) * 32 + q4];
            float4 g3 = *(const float4*)&sG[gb + (c4 * 4 + 3) * 32 + q4];
            v0.x += kv.x * g0.x; v0.y += kv.x * g0.y; v0.z += kv.x * g0.z; v0.w += kv.x * g0.w;
            v1.x += kv.y * g1.x; v1.y += kv.y * g1.y; v1.z += kv.y * g1.z; v1.w += kv.y * g1.w;
            v2.x += kv.z * g2.x; v2.y += kv.z * g2.y; v2.z += kv.z * g2.z; v2.w += kv.z * g2.w;
            v3.x += kv.w * g3.x; v3.y += kv.w * g3.y; v3.z += kv.w * g3.z; v3.w += kv.w * g3.w;
        }
        float4 m;
        m.x = v0.x + v1.x + v2.x + v3.x;
        m.y = v0.y + v1.y + v2.y + v3.y;
        m.z = v0.z + v1.z + v2.z + v3.z;
        m.w = v0.w + v1.w + v2.w + v3.w;
        float* ap = agg + (size_t)dst * WID + q4;
        unsafeAtomicAdd(ap + 0, m.x);
        unsafeAtomicAdd(ap + 1, m.y);
        unsafeAtomicAdd(ap + 2, m.z);
        unsafeAtomicAdd(ap + 3, m.w);
    }
}

// ---------------- node update (in place) + agg re-zero + hg regather + optional fc2 ----------------

__global__ __launch_bounds__(256) void k_node2(float* __restrict__ h,
        float* __restrict__ agg1, float* __restrict__ aggb,
        const float* __restrict__ inv1, const float* __restrict__ invb,
        const float* __restrict__ x, const float* __restrict__ fc1w,
        const float* __restrict__ fc1b,
        const float* __restrict__ rs, const float* __restrict__ bs,
        const int* __restrict__ arank1, const int* __restrict__ anodes1,
        const int* __restrict__ dna1, float* __restrict__ hg1,
        const int* __restrict__ arankb, const int* __restrict__ anodesb,
        const int* __restrict__ dnab, float* __restrict__ hgb,
        const float* __restrict__ fc2w, const float* __restrict__ fc2b,
        float* __restrict__ out, int do_out) {
    __shared__ float sR[1024];
    __shared__ float sB[32];
    for (int i = threadIdx.x; i < 1024; i += 256) sR[i] = rs[i];
    if (threadIdx.x < 32) sB[threadIdx.x] = bs[threadIdx.x];
    __syncthreads();
    int t = blockIdx.x * 256 + threadIdx.x;
    if (t >= NN * WID) return;
    int n = t >> 5, j = t & 31;
    float s = agg1[t] * inv1[n] + aggb[t] * invb[n] + sB[j];
    agg1[t] = 0.0f;           // ready for next depth (this thread's element only)
    aggb[t] = 0.0f;
    const float4* hv4 = (const float4*)(h + (size_t)n * WID);
#pragma unroll
    for (int q = 0; q < 8; q++) {
        float4 hv = hv4[q];
        s += hv.x * sR[(q * 4 + 0) * 32 + j];
        s += hv.y * sR[(q * 4 + 1) * 32 + j];
        s += hv.z * sR[(q * 4 + 2) * 32 + j];
        s += hv.w * sR[(q * 4 + 3) * 32 + j];
    }
    float h0v = x[n] * fc1w[j] + fc1b[j];
    float val = fmaxf(s, 0.0f) + h0v;
    h[t] = val;   // wave-lockstep: all row reads precede any store in program order
    int r1 = arank1[n];
    if (r1 < dna1[0] && anodes1[r1] == n)
        hg1[(r1 / NBL) * (32 * HSTR) + j * HSTR + (r1 % NBL)] = val;
    int rb = arankb[n];
    if (rb < dnab[0] && anodesb[rb] == n)
        hgb[(rb / NBL) * (32 * HSTR) + j * HSTR + (rb % NBL)] = val;
    if (do_out) {
        float r = val * fc2w[j];
#pragma unroll
        for (int m = 16; m >= 1; m >>= 1)
            r += __shfl_xor(r, m, 32);
        if (j == 0) out[n] = r + fc2b[0];
    }
}

// ---------------- launch ----------------

extern "C" void kernel_launch(void* const* d_in, const int* in_sizes, int n_in,
                              void* d_out, int out_size, void* d_ws, size_t ws_size,
                              hipStream_t stream) {
    const float* x    = (const float*)d_in[0];
    const int*   ei   = (const int*)d_in[1];
    const float* ea   = (const float*)d_in[2];
    const int*   eib  = (const int*)d_in[3];
    const float* eab  = (const float*)d_in[4];
    const float* fc1w = (const float*)d_in[5];
    const float* fc1b = (const float*)d_in[6];
    const float* fc2w = (const float*)d_in[7];
    const float* fc2b = (const float*)d_in[8];
    const float* k1w1 = (const float*)d_in[9];
    const float* k1b1 = (const float*)d_in[10];
    const float* k1w2 = (const float*)d_in[11];
    const float* k1b2 = (const float*)d_in[12];
    const float* k1w3 = (const float*)d_in[13];
    const float* k1b3 = (const float*)d_in[14];
    const float* root1= (const float*)d_in[15];
    const float* bias1= (const float*)d_in[16];
    const float* k2w1 = (const float*)d_in[17];
    const float* k2b1 = (const float*)d_in[18];
    const float* k2w2 = (const float*)d_in[19];
    const float* k2b2 = (const float*)d_in[20];
    const float* k2w3 = (const float*)d_in[21];
    const float* k2b3 = (const float*)d_in[22];
    const float* root2= (const float*)d_in[23];
    const float* bias2= (const float*)d_in[24];

    float* p = (float*)d_ws;
    auto alloc = [&](size_t nflt) { float* r = p; p += nflt; return r; };
    int nblkA = (NN + NBL - 1) / NBL;           // 2223
    float* K1   = alloc((size_t)EM * KW);     // sorted (by src) order
    float* Kb   = alloc((size_t)EBN * KW);
    float* hA   = alloc((size_t)NN * WID);
    float* agg1 = alloc((size_t)NN * WID);    // agg1+aggb contiguous
    float* aggb = alloc((size_t)NN * WID);
    float* hg1  = alloc((size_t)(nblkA + 2) * 32 * HSTR);
    float* hgb  = alloc((size_t)(nblkA + 2) * 32 * HSTR);
    float* inv1 = alloc(NN);
    float* invb = alloc(NN);
    float* rs   = alloc(1024);
    float* bs   = alloc(32);
    int*   cnt1 = (int*)alloc(NN);   // cnt1,cntb,cs1,csb contiguous: single memset
    int*   cntb = (int*)alloc(NN);
    int*   cs1  = (int*)alloc(NN);
    int*   csb  = (int*)alloc(NN);
    int*   cur1 = (int*)alloc(NN);
    int*   curb = (int*)alloc(NN);
    int*   arank1 = (int*)alloc(NN);
    int*   arankb = (int*)alloc(NN);
    int*   anodes1= (int*)alloc(NN);
    int*   anodesb= (int*)alloc(NN);
    int*   aoff1  = (int*)alloc(NN + 1);
    int*   aoffb  = (int*)alloc(NN + 1);
    int*   dna1   = (int*)alloc(1);
    int*   dnab   = (int*)alloc(1);
    int*   perm1= (int*)alloc(EM);
    int*   permb= (int*)alloc(EBN);
    int*   rk1  = (int*)alloc(EM);
    int*   dst1 = (int*)alloc(EM);
    int*   rkb  = (int*)alloc(EBN);
    int*   dstb = (int*)alloc(EBN);
    float* M1   = alloc(32 * GC);
    float* M2   = alloc(32 * GC);

    hipMemsetAsync(cnt1, 0, 4 * NN * sizeof(int), stream);
    k_count4<<<(2 * EM + 2 * EBN + 255) / 256, 256, 0, stream>>>(ei, eib, cs1, cnt1, csb, cntb);
    k_scan3<<<2, 1024, 0, stream>>>(cs1, cur1, arank1, anodes1, aoff1, dna1, EM,
                                    csb, curb, arankb, anodesb, aoffb, dnab, EBN);
    k_scatter3<<<(EM + EBN + 255) / 256, 256, 0, stream>>>(ei, cur1, perm1, eib, curb, permb);
    k_permidx3<<<(EM + EBN + 2 * NN + 255) / 256, 256, 0, stream>>>(
        ei, perm1, arank1, rk1, dst1, eib, permb, arankb, rkb, dstb,
        cnt1, inv1, cntb, invb);
    int nmb = (EM + 255) / 256;
    k_mlp3<<<nmb + (EBN + 255) / 256, 256, 0, stream>>>(
        ea, perm1, k1w1, k1b1, k1w2, k1b2, K1,
        eab, permb, k2w1, k2b1, k2w2, k2b2, Kb, nmb);
    k_permM3<<<(64 * GC + 1056 + 255) / 256, 256, 0, stream>>>(
        k1w3, k1b3, M1, k2w3, k2b3, M2, root1, bias1, root2, bias2, rs, bs);
    k_h0g<<<(2 * NN * WID + 255) / 256, 256, 0, stream>>>(x, fc1w, fc1b, hA,
                                                          arank1, anodes1, dna1, hg1,
                                                          arankb, anodesb, dnab, hgb,
                                                          agg1);

    int fgrid = nblkA * 2;                      // main + boundary halves
    for (int d = 0; d < NDEPTH; d++) {
        k_fuse3<<<fgrid, TPB_F, 0, stream>>>(rk1, dst1, aoff1, dna1, K1, M1, hg1, agg1,
                                             rkb, dstb, aoffb, dnab, Kb, M2, hgb, aggb,
                                             nblkA);
        k_node2<<<(NN * WID + 255) / 256, 256, 0, stream>>>(hA, agg1, aggb, inv1, invb,
                                                            x, fc1w, fc1b, rs, bs,
                                                            arank1, anodes1, dna1, hg1,
                                                            arankb, anodesb, dnab, hgb,
                                                            fc2w, fc2b, (float*)d_out,
                                                            (d == NDEPTH - 1) ? 1 : 0);
    }
}